// Round 3
// baseline (486.421 us; speedup 1.0000x reference)
//
#include <hip/hip_runtime.h>
#include <cstdint>
#include <cstddef>

#define DDIM 4096          // hidden dim
#define D4   1024          // float4 per row
#define NE   16            // experts
#define KC4  128           // K-chunk in float4 (= 512 floats)
#define NCHUNK 8           // DDIM / 512
#define CHUNK 256          // pass-B tokens per block

// ---------------------------------------------------------------------------
// Pass A: logits GEMV + bias + top-2 softmax renorm + dispatch tensor +
// packed per-token expert-pair byte for pass B.
// Block = 4 waves = 16 tokens. K is processed in 8 chunks of 512 floats;
// each chunk's W-slice (16 experts x 512 floats = 32 KB) is staged in LDS
// cooperatively, so the inner loop reads W at LDS latency instead of L2.
// One wave = 4 tokens; K split across all 64 lanes (float4 idx = lane + 64*ii).
// acc[j], j = t*16+e. Split-exchange butterfly leaves the full sum for
// (t = lane>>4, e = lane&15) in acc[0] -> coalesced epilogue.
// ---------------------------------------------------------------------------
__global__ __launch_bounds__(256, 4) void router_pass_a(
    const float* __restrict__ x, const float* __restrict__ W,
    const float* __restrict__ b, float* __restrict__ out,
    unsigned char* __restrict__ packed, int T)
{
    __shared__ float4 shW[NE * KC4];   // 32 KB

    const int tid   = (int)threadIdx.x;
    const int lane  = tid & 63;
    const int wave  = (int)blockIdx.x * 4 + (tid >> 6);
    const int tok0  = wave * 4;

    const float4* __restrict__ x4 = (const float4*)x;
    const float4* __restrict__ W4 = (const float4*)W;
    const float4* xr = x4 + (size_t)tok0 * D4;

    float acc[64];
#pragma unroll
    for (int j = 0; j < 64; ++j) acc[j] = 0.f;

    for (int kc = 0; kc < NCHUNK; ++kc) {
        // cooperative W-chunk stage: 2048 float4, 8 per thread (reg round-trip)
        float4 tmp[8];
#pragma unroll
        for (int i = 0; i < 8; ++i) {
            const int j = tid + (i << 8);                 // 0..2047
            const int e = j >> 7, kf = j & 127;
            tmp[i] = W4[(size_t)e * D4 + kc * KC4 + kf];
        }
        __syncthreads();          // prior chunk's LDS reads done before overwrite
#pragma unroll
        for (int i = 0; i < 8; ++i)
            shW[tid + (i << 8)] = tmp[i];
        __syncthreads();

        const float4* xc = xr + kc * KC4;
#pragma unroll
        for (int ii = 0; ii < 2; ++ii) {
            const int f4 = lane + (ii << 6);
            float4 a0 = xc[f4];
            float4 a1 = xc[f4 + D4];
            float4 a2 = xc[f4 + 2 * D4];
            float4 a3 = xc[f4 + 3 * D4];
#pragma unroll
            for (int e = 0; e < NE; ++e) {
                float4 w = shW[e * KC4 + f4];
                acc[e]      += a0.x * w.x + a0.y * w.y + a0.z * w.z + a0.w * w.w;
                acc[16 + e] += a1.x * w.x + a1.y * w.y + a1.z * w.z + a1.w * w.w;
                acc[32 + e] += a2.x * w.x + a2.y * w.y + a2.z * w.z + a2.w * w.w;
                acc[48 + e] += a3.x * w.x + a3.y * w.y + a3.z * w.z + a3.w * w.w;
            }
        }
    }

    // split-exchange reduction: after all stages, acc[0] holds the full sum
    // for index j == lane (t = lane>>4, e = lane&15).
#pragma unroll
    for (int m = 32; m >= 1; m >>= 1) {
        const bool hi = (lane & m) != 0;
#pragma unroll
        for (int i = 0; i < m; ++i) {
            float send = hi ? acc[i] : acc[i + m];
            float keep = hi ? acc[i + m] : acc[i];
            acc[i] = keep + __shfl_xor(send, m, 64);
        }
    }

    const int e = lane & 15;
    const float logit = acc[0] + b[e];
    out[(size_t)tok0 * NE + lane] = logit;   // 64 consecutive floats per wave

    // top-2 (value, index) merge across the 16-lane group; lower index wins ties
    float m1 = logit; int i1 = e;
    float m2 = -__builtin_inff(); int i2 = NE;
#pragma unroll
    for (int m = 1; m <= 8; m <<= 1) {
        float om1 = __shfl_xor(m1, m, 64); int oi1 = __shfl_xor(i1, m, 64);
        float om2 = __shfl_xor(m2, m, 64); int oi2 = __shfl_xor(i2, m, 64);
        bool aFirst = (m1 > om1) || (m1 == om1 && i1 < oi1);
        float n1v = aFirst ? m1 : om1;  int n1i = aFirst ? i1 : oi1;
        float l1v = aFirst ? om1 : m1;  int l1i = aFirst ? oi1 : i1;  // loser of firsts
        float c2v = aFirst ? m2 : om2;  int c2i = aFirst ? i2 : oi2;  // winner's 2nd
        bool s = (l1v > c2v) || (l1v == c2v && l1i < c2i);
        m1 = n1v; i1 = n1i;
        m2 = s ? l1v : c2v; i2 = s ? l1i : c2i;
    }

    const float q  = expf(m2 - m1);          // p2/p1
    const float r1 = 1.f / (1.f + q);
    const float r2 = q / (1.f + q);
    float* __restrict__ disp = out + (size_t)T * NE;
    disp[(size_t)tok0 * NE + lane] = (e == i1) ? r1 : ((e == i2) ? r2 : 0.f);

    if (e == 0)
        packed[tok0 + (lane >> 4)] = (unsigned char)(i1 | (i2 << 4));
}

// ---------------------------------------------------------------------------
// Pass B1: per-chunk expert histogram + fill expert_indices rows with -1.
// ---------------------------------------------------------------------------
__global__ __launch_bounds__(CHUNK) void router_count_fill(
    const unsigned char* __restrict__ packed, int* __restrict__ gcounts,
    float* __restrict__ idxout, int T)
{
    const int c = (int)blockIdx.x;
    const int tid = (int)threadIdx.x;
    __shared__ int cnt[NE];
    if (tid < NE) cnt[tid] = 0;
    __syncthreads();

    const int t = c * CHUNK + tid;
    const unsigned p = packed[t];
    atomicAdd(&cnt[p & 15], 1);
    atomicAdd(&cnt[p >> 4], 1);

#pragma unroll
    for (int ee = 0; ee < NE; ++ee)
        idxout[(size_t)ee * T + t] = -1.0f;

    __syncthreads();
    if (tid < NE) gcounts[c * NE + tid] = cnt[tid];
}

// ---------------------------------------------------------------------------
// Pass B2: exclusive prefix over 64 chunks per expert. 16 waves, wave=expert,
// lane=chunk. Requires T/CHUNK == 64.
// ---------------------------------------------------------------------------
__global__ __launch_bounds__(1024) void router_scan(
    const int* __restrict__ gcounts, int* __restrict__ goffs)
{
    const int e = (int)(threadIdx.x >> 6);
    const int c = (int)(threadIdx.x & 63);
    int v = gcounts[c * NE + e];
    const int own = v;
#pragma unroll
    for (int sh = 1; sh < 64; sh <<= 1) {
        int t = __shfl_up(v, sh, 64);
        if (c >= sh) v += t;
    }
    goffs[c * NE + e] = v - own;
}

// ---------------------------------------------------------------------------
// Pass B3: stable scatter of token ids into expert rows.
// ---------------------------------------------------------------------------
__global__ __launch_bounds__(CHUNK) void router_scatter(
    const unsigned char* __restrict__ packed, const int* __restrict__ goffs,
    float* __restrict__ idxout, int T)
{
    const int c = (int)blockIdx.x;
    const int tid = (int)threadIdx.x;
    const int lane = tid & 63;
    const int wid = tid >> 6;               // 0..3
    __shared__ int wtot[CHUNK / 64][NE];

    const int t = c * CHUNK + tid;
    const unsigned p = packed[t];
    const int e1 = (int)(p & 15);
    const int e2 = (int)(p >> 4);

    unsigned long long bal[NE];
#pragma unroll
    for (int ee = 0; ee < NE; ++ee)
        bal[ee] = __ballot((e1 == ee) || (e2 == ee));

    if (lane < NE) wtot[wid][lane] = __popcll(bal[lane]);
    __syncthreads();

    const unsigned long long lt = (1ull << lane) - 1ull;
    int r1 = __popcll(bal[e1] & lt);
    int r2 = __popcll(bal[e2] & lt);
    for (int w = 0; w < wid; ++w) { r1 += wtot[w][e1]; r2 += wtot[w][e2]; }

    idxout[(size_t)e1 * T + goffs[c * NE + e1] + r1] = (float)t;
    idxout[(size_t)e2 * T + goffs[c * NE + e2] + r2] = (float)t;
}

extern "C" void kernel_launch(void* const* d_in, const int* in_sizes, int n_in,
                              void* d_out, int out_size, void* d_ws, size_t ws_size,
                              hipStream_t stream)
{
    const float* x = (const float*)d_in[0];
    const float* W = (const float*)d_in[1];
    const float* b = (const float*)d_in[2];
    float* out = (float*)d_out;

    const int T = in_sizes[0] / DDIM;       // 16384 tokens

    unsigned char* packed = (unsigned char*)d_ws;
    int* gcounts = (int*)((char*)d_ws + (((size_t)T + 255) & ~(size_t)255));
    int* goffs   = gcounts + (T / CHUNK) * NE;

    float* idxout = out + (size_t)2 * T * NE;

    // Pass A: block = 4 waves = 16 tokens -> T/16 blocks
    router_pass_a<<<T / 16, 256, 0, stream>>>(x, W, b, out, packed, T);

    // Pass B: count+fill, scan, scatter
    router_count_fill<<<T / CHUNK, CHUNK, 0, stream>>>(packed, gcounts, idxout, T);
    router_scan<<<1, 1024, 0, stream>>>(gcounts, goffs);
    router_scatter<<<T / CHUNK, CHUNK, 0, stream>>>(packed, goffs, idxout, T);
}